// Round 4
// baseline (616.074 us; speedup 1.0000x reference)
//
#include <hip/hip_runtime.h>
#include <math.h>

#define NF 8192

// ---------- complex helpers ----------
__device__ __forceinline__ int phys(int e) { return e ^ (((e >> 4) & 7) << 1); }

__device__ __forceinline__ float2 cmul(float2 a, float2 b) {
    return make_float2(a.x*b.x - a.y*b.y, a.x*b.y + a.y*b.x);
}
__device__ __forceinline__ float2 cmulc(float2 a, float2 b) { // a * conj(b)
    return make_float2(a.x*b.x + a.y*b.y, a.y*b.x - a.x*b.y);
}
__device__ __forceinline__ float2 cadd(float2 a, float2 b){ return make_float2(a.x+b.x, a.y+b.y); }
__device__ __forceinline__ float2 csub(float2 a, float2 b){ return make_float2(a.x-b.x, a.y-b.y); }
__device__ __forceinline__ float2 mnegi(float2 a){ return make_float2(a.y, -a.x); }   // * (-i)
__device__ __forceinline__ float2 mposi(float2 a){ return make_float2(-a.y, a.x); }   // * (+i)
#define RSQ2 0.70710678118654752f
__device__ __forceinline__ float2 mw81 (float2 a){ return make_float2( RSQ2*(a.x+a.y),  RSQ2*(a.y-a.x)); } // * e^{-i pi/4}
__device__ __forceinline__ float2 mw83 (float2 a){ return make_float2( RSQ2*(a.y-a.x), -RSQ2*(a.x+a.y)); } // * e^{-3i pi/4}
__device__ __forceinline__ float2 mw81c(float2 a){ return make_float2( RSQ2*(a.x-a.y),  RSQ2*(a.x+a.y)); } // * e^{+i pi/4}
__device__ __forceinline__ float2 mw83c(float2 a){ return make_float2(-RSQ2*(a.x+a.y),  RSQ2*(a.x-a.y)); } // * e^{+3i pi/4}

// w16 constants
#define C16_1 0.92387953251128674f
#define S16_1 0.38268343236508978f
#define C16_2 0.70710678118654752f

// base twiddle exp(-2*pi*i*ts/8192) via HW transcendentals (input in revolutions, |arg|<1)
__device__ __forceinline__ float2 twbase(int ts) {
    float fa = (float)ts * (1.0f/8192.0f);
    return make_float2(__builtin_amdgcn_cosf(fa), -__builtin_amdgcn_sinf(fa));
}

// DIF radix-8 core. After: y0=v0 y1=v4 y2=v2 y3=v6 y4=v1 y5=v5 y6=v3 y7=v7
__device__ __forceinline__ void dif8_core(float2& v0, float2& v1, float2& v2, float2& v3,
                                          float2& v4, float2& v5, float2& v6, float2& v7) {
    float2 t;
    t = csub(v0, v4); v0 = cadd(v0, v4); v4 = t;
    t = csub(v1, v5); v1 = cadd(v1, v5); v5 = mw81(t);
    t = csub(v2, v6); v2 = cadd(v2, v6); v6 = mnegi(t);
    t = csub(v3, v7); v3 = cadd(v3, v7); v7 = mw83(t);
    t = csub(v0, v2); v0 = cadd(v0, v2); v2 = t;
    t = csub(v1, v3); v1 = cadd(v1, v3); v3 = mnegi(t);
    t = csub(v4, v6); v4 = cadd(v4, v6); v6 = t;
    t = csub(v5, v7); v5 = cadd(v5, v7); v7 = mnegi(t);
    t = csub(v0, v1); v0 = cadd(v0, v1); v1 = t;
    t = csub(v2, v3); v2 = cadd(v2, v3); v3 = t;
    t = csub(v4, v5); v4 = cadd(v4, v5); v5 = t;
    t = csub(v6, v7); v6 = cadd(v6, v7); v7 = t;
}

// DIT radix-8 core. Inputs v0=y0 v1=y4*c4 v2=y2*c2 v3=y6*c6 v4=y1*c1 v5=y5*c5 v6=y3*c3 v7=y7*c7
__device__ __forceinline__ void dit8_core(float2& v0, float2& v1, float2& v2, float2& v3,
                                          float2& v4, float2& v5, float2& v6, float2& v7) {
    float2 t;
    t = csub(v0, v1); v0 = cadd(v0, v1); v1 = t;
    t = csub(v2, v3); v2 = cadd(v2, v3); v3 = t;
    t = csub(v4, v5); v4 = cadd(v4, v5); v5 = t;
    t = csub(v6, v7); v6 = cadd(v6, v7); v7 = t;
    t = v2;        v2 = csub(v0, t); v0 = cadd(v0, t);
    t = mposi(v3); v3 = csub(v1, t); v1 = cadd(v1, t);
    t = v6;        v6 = csub(v4, t); v4 = cadd(v4, t);
    t = mposi(v7); v7 = csub(v5, t); v5 = cadd(v5, t);
    t = v4;        v4 = csub(v0, t); v0 = cadd(v0, t);
    t = mw81c(v5); v5 = csub(v1, t); v1 = cadd(v1, t);
    t = mposi(v6); v6 = csub(v2, t); v2 = cadd(v2, t);
    t = mw83c(v7); v7 = csub(v3, t); v3 = cadd(v3, t);
}

// compute w^1..w^7 from base ts
#define TW_POWERS(ts) \
    float2 w1 = twbase(ts); \
    float2 w2 = cmul(w1, w1); \
    float2 w3 = cmul(w2, w1); \
    float2 w4 = cmul(w2, w2); \
    float2 w5 = cmul(w3, w2); \
    float2 w6 = cmul(w3, w3); \
    float2 w7 = cmul(w4, w3);

// ---------- radix-8 LDS passes (512 threads) ----------
template<int M, int LM>
__device__ __forceinline__ void fwd8_lds(float2* Z, int tid) {
    #pragma unroll
    for (int q = 0; q < 2; ++q) {
        int beta = tid + q*512;
        int i    = beta & (M-1);
        int base = ((beta >> LM) << (LM+3)) + i;
        float2 v0 = Z[phys(base        )];
        float2 v1 = Z[phys(base + 1*M)];
        float2 v2 = Z[phys(base + 2*M)];
        float2 v3 = Z[phys(base + 3*M)];
        float2 v4 = Z[phys(base + 4*M)];
        float2 v5 = Z[phys(base + 5*M)];
        float2 v6 = Z[phys(base + 6*M)];
        float2 v7 = Z[phys(base + 7*M)];
        dif8_core(v0,v1,v2,v3,v4,v5,v6,v7);
        TW_POWERS((NF >> (LM+3)) * i)
        Z[phys(base        )] = v0;
        Z[phys(base + 4*M)] = cmul(v1, w4);
        Z[phys(base + 2*M)] = cmul(v2, w2);
        Z[phys(base + 6*M)] = cmul(v3, w6);
        Z[phys(base + 1*M)] = cmul(v4, w1);
        Z[phys(base + 5*M)] = cmul(v5, w5);
        Z[phys(base + 3*M)] = cmul(v6, w3);
        Z[phys(base + 7*M)] = cmul(v7, w7);
    }
}

template<int M, int LM>
__device__ __forceinline__ void inv8_lds(float2* Z, int tid) {
    #pragma unroll
    for (int q = 0; q < 2; ++q) {
        int beta = tid + q*512;
        int i    = beta & (M-1);
        int base = ((beta >> LM) << (LM+3)) + i;
        TW_POWERS((NF >> (LM+3)) * i)
        float2 v0 = Z[phys(base        )];
        float2 v1 = cmulc(Z[phys(base + 4*M)], w4);
        float2 v2 = cmulc(Z[phys(base + 2*M)], w2);
        float2 v3 = cmulc(Z[phys(base + 6*M)], w6);
        float2 v4 = cmulc(Z[phys(base + 1*M)], w1);
        float2 v5 = cmulc(Z[phys(base + 5*M)], w5);
        float2 v6 = cmulc(Z[phys(base + 3*M)], w3);
        float2 v7 = cmulc(Z[phys(base + 7*M)], w7);
        dit8_core(v0,v1,v2,v3,v4,v5,v6,v7);
        Z[phys(base        )] = v0;
        Z[phys(base + 1*M)] = v1;
        Z[phys(base + 2*M)] = v2;
        Z[phys(base + 3*M)] = v3;
        Z[phys(base + 4*M)] = v4;
        Z[phys(base + 5*M)] = v5;
        Z[phys(base + 6*M)] = v6;
        Z[phys(base + 7*M)] = v7;
    }
}

// Full forward FFT -> pointwise *A (scrambled, transposed layout) -> inverse FFT.
// vin[q*4+l] = complex input at position p = tid + q*512 + l*1024 (p < 4096; rest zero).
// vout same mapping (unscaled). Caller must __syncthreads() before reusing Z.
__device__ __forceinline__ void fft8192_conv(float2* Z, int tid, const float4* __restrict__ A4,
                                             const float2 (&vin)[8], float2 (&vout)[8])
{
    // P1: fused first fwd8 pass (M=1024), upper half of input zero
    #pragma unroll
    for (int q = 0; q < 2; ++q) {
        int i = tid + q*512;
        float2 v0 = vin[q*4+0];
        float2 v1 = vin[q*4+1];
        float2 v2 = vin[q*4+2];
        float2 v3 = vin[q*4+3];
        float2 v4 = v0;
        float2 v5 = mw81(v1);
        float2 v6 = mnegi(v2);
        float2 v7 = mw83(v3);
        float2 t;
        t = csub(v0, v2); v0 = cadd(v0, v2); v2 = t;
        t = csub(v1, v3); v1 = cadd(v1, v3); v3 = mnegi(t);
        t = csub(v4, v6); v4 = cadd(v4, v6); v6 = t;
        t = csub(v5, v7); v5 = cadd(v5, v7); v7 = mnegi(t);
        t = csub(v0, v1); v0 = cadd(v0, v1); v1 = t;
        t = csub(v2, v3); v2 = cadd(v2, v3); v3 = t;
        t = csub(v4, v5); v4 = cadd(v4, v5); v5 = t;
        t = csub(v6, v7); v6 = cadd(v6, v7); v7 = t;
        TW_POWERS(i)
        Z[phys(i        )] = v0;
        Z[phys(i + 4096)] = cmul(v1, w4);
        Z[phys(i + 2048)] = cmul(v2, w2);
        Z[phys(i + 6144)] = cmul(v3, w6);
        Z[phys(i + 1024)] = cmul(v4, w1);
        Z[phys(i + 5120)] = cmul(v5, w5);
        Z[phys(i + 3072)] = cmul(v6, w3);
        Z[phys(i + 7168)] = cmul(v7, w7);
    }
    __syncthreads();
    fwd8_lds<128, 7>(Z, tid);  __syncthreads();
    fwd8_lds<16,  4>(Z, tid);  __syncthreads();

    // P4: fused fwd8<2,1> + fwd2 + (*A) + inv2 + inv8<2,1> — register chunk of 16
    {
        int c = tid, sw4 = c & 7;
        float4* Z4 = reinterpret_cast<float4*>(Z);
        float2 z[16];
        #pragma unroll
        for (int j = 0; j < 8; ++j) {
            float4 wv = Z4[c*8 + (j ^ sw4)];
            z[2*j]   = make_float2(wv.x, wv.y);
            z[2*j+1] = make_float2(wv.z, wv.w);
        }
        dif8_core(z[0],z[2],z[4],z[6],z[8],z[10],z[12],z[14]);
        dif8_core(z[1],z[3],z[5],z[7],z[9],z[11],z[13],z[15]);
        #define P4K(k, ZE, ZO, WR, WI) { \
            float2 w = make_float2((WR)*(ZO).x - (WI)*(ZO).y, (WR)*(ZO).y + (WI)*(ZO).x); \
            float2 pp = cadd(ZE, w), rr = csub(ZE, w); \
            float4 av = A4[(k)*512 + c]; \
            pp = cmul(pp, make_float2(av.x, av.y)); \
            rr = cmul(rr, make_float2(av.z, av.w)); \
            ZE = cadd(pp, rr); \
            ZO = csub(pp, rr); }
        { float2 pp = cadd(z[0], z[1]), rr = csub(z[0], z[1]);
          float4 av = A4[0*512 + c];
          pp = cmul(pp, make_float2(av.x, av.y));
          rr = cmul(rr, make_float2(av.z, av.w));
          z[0] = cadd(pp, rr); z[1] = csub(pp, rr); }
        P4K(1, z[8],  z[9],   C16_1, -S16_1)
        P4K(2, z[4],  z[5],   C16_2, -C16_2)
        P4K(3, z[12], z[13],  S16_1, -C16_1)
        { float2 w = mnegi(z[3]);
          float2 pp = cadd(z[2], w), rr = csub(z[2], w);
          float4 av = A4[4*512 + c];
          pp = cmul(pp, make_float2(av.x, av.y));
          rr = cmul(rr, make_float2(av.z, av.w));
          z[2] = cadd(pp, rr); z[3] = csub(pp, rr); }
        P4K(5, z[10], z[11], -S16_1, -C16_1)
        P4K(6, z[6],  z[7],  -C16_2, -C16_2)
        P4K(7, z[14], z[15], -C16_1, -S16_1)
        #undef P4K
        // conj twiddles on odd legs for the inverse radix-8 (i=1 butterfly)
        z[3]  = mposi(z[3]);
        z[5]  = cmul(z[5],  make_float2( C16_2,  C16_2));
        z[7]  = cmul(z[7],  make_float2(-C16_2,  C16_2));
        z[9]  = cmul(z[9],  make_float2( C16_1,  S16_1));
        z[11] = cmul(z[11], make_float2(-S16_1,  C16_1));
        z[13] = cmul(z[13], make_float2( S16_1,  C16_1));
        z[15] = cmul(z[15], make_float2(-C16_1,  S16_1));
        dit8_core(z[0],z[2],z[4],z[6],z[8],z[10],z[12],z[14]);
        dit8_core(z[1],z[3],z[5],z[7],z[9],z[11],z[13],z[15]);
        #pragma unroll
        for (int j = 0; j < 8; ++j)
            Z4[c*8 + (j ^ sw4)] = make_float4(z[2*j].x, z[2*j].y, z[2*j+1].x, z[2*j+1].y);
    }
    __syncthreads();
    inv8_lds<16,  4>(Z, tid);  __syncthreads();
    inv8_lds<128, 7>(Z, tid);  __syncthreads();

    // P7: fused inv8<1024,10> (only legs 0..3 are kept) -> registers
    #pragma unroll
    for (int q = 0; q < 2; ++q) {
        int i = tid + q*512;
        TW_POWERS(i)
        float2 v0 = Z[phys(i        )];
        float2 v1 = cmulc(Z[phys(i + 4096)], w4);
        float2 v2 = cmulc(Z[phys(i + 2048)], w2);
        float2 v3 = cmulc(Z[phys(i + 6144)], w6);
        float2 v4 = cmulc(Z[phys(i + 1024)], w1);
        float2 v5 = cmulc(Z[phys(i + 5120)], w5);
        float2 v6 = cmulc(Z[phys(i + 3072)], w3);
        float2 v7 = cmulc(Z[phys(i + 7168)], w7);
        float2 t;
        t = csub(v0, v1); v0 = cadd(v0, v1); v1 = t;
        t = csub(v2, v3); v2 = cadd(v2, v3); v3 = t;
        t = csub(v4, v5); v4 = cadd(v4, v5); v5 = t;
        t = csub(v6, v7); v6 = cadd(v6, v7); v7 = t;
        t = v2;        v2 = csub(v0, t); v0 = cadd(v0, t);
        t = mposi(v3); v3 = csub(v1, t); v1 = cadd(v1, t);
        t = v6;        v6 = csub(v4, t); v4 = cadd(v4, t);
        t = mposi(v7); v7 = csub(v5, t); v5 = cadd(v5, t);
        vout[q*4+0] = cadd(v0, v4);
        vout[q*4+1] = cadd(v1, mw81c(v5));
        vout[q*4+2] = cadd(v2, mposi(v6));
        vout[q*4+3] = cadd(v3, mw83c(v7));
    }
}

// ---------- kernels ----------

// Position-MLP: a[c][e] = decay(e) * rpe(offset(e))[c].  512 blocks x 512 thr, 16 pos/block.
// Weights in LDS with paired-k layout: [k/2][lane][2] so the dot loop reads b64.
__global__ __launch_bounds__(512) void rpe_kernel(
    const float* __restrict__ pw,  const float* __restrict__ pb,
    const float* __restrict__ lws, const float* __restrict__ lbs,
    const float* __restrict__ ow,  const float* __restrict__ ob,
    float* __restrict__ a_buf)
{
    __shared__ float sW2[3][32][64][2];   // 48 KB, layer weights paired-k
    __shared__ float sWo2[32][64][2];     // 16 KB, out-proj chunk paired-k
    __shared__ float sB[3][64];
    __shared__ float sPW[64], sPB[64];
    __shared__ float sAct[8][2][64];      // wave-private activation rows
    int tid = threadIdx.x;
    for (int idx = tid; idx < 3*64*64; idx += 512) {
        int L = idx >> 12, rem = idx & 4095, k = rem >> 6, c = rem & 63;
        sW2[L][k >> 1][c][k & 1] = lws[idx];
    }
    if (tid < 192) ((float*)sB)[tid] = lbs[tid];
    if (tid < 64) { sPW[tid] = pw[tid]; sPB[tid] = pb[tid]; }
    __syncthreads();

    int wv = tid >> 6, lane = tid & 63;
    int e0 = blockIdx.x * 16 + wv * 2;
    float xv[2], dec[2];
    #pragma unroll
    for (int s = 0; s < 2; ++s) {
        int e = e0 + s;
        float p = (e == 4096) ? 0.f : ((e < 4096) ? (float)e : (float)(e - 8192));
        int m = (e < 4096) ? e : (8192 - e);
        if (e == 4096) m = 0;
        dec[s] = exp2f(-0.0014434309482562475f * (float)m);   // log2(0.999)
        xv[s] = fmaf(p, sPW[lane], sPB[lane]);
    }

    #pragma unroll
    for (int L = 0; L < 3; ++L) {
        #pragma unroll
        for (int s = 0; s < 2; ++s) {
            float v = xv[s];
            float ss = v * v;
            #pragma unroll
            for (int o = 1; o < 64; o <<= 1) ss += __shfl_xor(ss, o);
            sAct[wv][s][lane] = fmaxf(v / (sqrtf(ss) * 0.125f + 1e-8f), 0.f);
            // wave-private LDS RAW: lgkmcnt ordering suffices, no barrier
            float y = sB[L][lane];
            const float2* ap = reinterpret_cast<const float2*>(sAct[wv][s]);
            const float2* wp = reinterpret_cast<const float2*>(sW2[L]);
            #pragma unroll
            for (int kk = 0; kk < 32; ++kk) {
                float2 a2 = ap[kk];                 // broadcast
                float2 ww = wp[kk*64 + lane];       // b64, 2-way (free)
                y = fmaf(a2.x, ww.x, y);
                y = fmaf(a2.y, ww.y, y);
            }
            xv[s] = y;
        }
    }
    #pragma unroll
    for (int s = 0; s < 2; ++s) {
        float v = xv[s];
        float ss = v * v;
        #pragma unroll
        for (int o = 1; o < 64; o <<= 1) ss += __shfl_xor(ss, o);
        sAct[wv][s][lane] = fmaxf(v / (sqrtf(ss) * 0.125f + 1e-8f), 0.f);
    }
    // out projection: 8 chunks of 64 channels
    for (int qq = 0; qq < 8; ++qq) {
        __syncthreads();
        for (int idx = tid; idx < 4096; idx += 512) {
            int k = idx >> 6, c = idx & 63;
            sWo2[k >> 1][c][k & 1] = ow[(size_t)k*512 + qq*64 + c];
        }
        __syncthreads();
        #pragma unroll
        for (int s = 0; s < 2; ++s) {
            float y = ob[qq*64 + lane];
            const float2* ap = reinterpret_cast<const float2*>(sAct[wv][s]);
            const float2* wp = reinterpret_cast<const float2*>(sWo2);
            #pragma unroll
            for (int kk = 0; kk < 32; ++kk) {
                float2 a2 = ap[kk];
                float2 ww = wp[kk*64 + lane];
                y = fmaf(a2.x, ww.x, y);
                y = fmaf(a2.y, ww.y, y);
            }
            a_buf[(size_t)(qq*64 + lane)*NF + (e0 + s)] = y * dec[s];
        }
    }
}

// FFT of each kernel column -> scrambled-order spectrum, stored transposed [k][c].
__global__ __launch_bounds__(512, 4) void afft_kernel(
    const float* __restrict__ a_buf, float2* __restrict__ Afft)
{
    __shared__ __align__(16) float2 Z[NF];   // 64 KB
    int cc = blockIdx.x, tid = threadIdx.x;
    const float* col = a_buf + (size_t)cc * NF;
    // A1: fused load + fwd8<1024,10>
    #pragma unroll
    for (int q = 0; q < 2; ++q) {
        int i = tid + q*512;
        float2 v0 = make_float2(col[i       ], 0.f);
        float2 v1 = make_float2(col[i + 1024], 0.f);
        float2 v2 = make_float2(col[i + 2048], 0.f);
        float2 v3 = make_float2(col[i + 3072], 0.f);
        float2 v4 = make_float2(col[i + 4096], 0.f);
        float2 v5 = make_float2(col[i + 5120], 0.f);
        float2 v6 = make_float2(col[i + 6144], 0.f);
        float2 v7 = make_float2(col[i + 7168], 0.f);
        dif8_core(v0,v1,v2,v3,v4,v5,v6,v7);
        TW_POWERS(i)
        Z[phys(i        )] = v0;
        Z[phys(i + 4096)] = cmul(v1, w4);
        Z[phys(i + 2048)] = cmul(v2, w2);
        Z[phys(i + 6144)] = cmul(v3, w6);
        Z[phys(i + 1024)] = cmul(v4, w1);
        Z[phys(i + 5120)] = cmul(v5, w5);
        Z[phys(i + 3072)] = cmul(v6, w3);
        Z[phys(i + 7168)] = cmul(v7, w7);
    }
    __syncthreads();
    fwd8_lds<128, 7>(Z, tid);  __syncthreads();
    fwd8_lds<16,  4>(Z, tid);  __syncthreads();
    // A4: fused fwd8<2,1> + fwd2 + transposed store
    {
        int c = tid, sw4 = c & 7;
        float4* Z4 = reinterpret_cast<float4*>(Z);
        float4* oc4 = reinterpret_cast<float4*>(Afft + (size_t)cc * NF);
        float2 z[16];
        #pragma unroll
        for (int j = 0; j < 8; ++j) {
            float4 wv = Z4[c*8 + (j ^ sw4)];
            z[2*j]   = make_float2(wv.x, wv.y);
            z[2*j+1] = make_float2(wv.z, wv.w);
        }
        dif8_core(z[0],z[2],z[4],z[6],z[8],z[10],z[12],z[14]);
        dif8_core(z[1],z[3],z[5],z[7],z[9],z[11],z[13],z[15]);
        #define A4K(k, ZE, ZO, WR, WI) { \
            float2 w = make_float2((WR)*(ZO).x - (WI)*(ZO).y, (WR)*(ZO).y + (WI)*(ZO).x); \
            float2 pp = cadd(ZE, w), rr = csub(ZE, w); \
            oc4[(k)*512 + c] = make_float4(pp.x, pp.y, rr.x, rr.y); }
        { float2 pp = cadd(z[0], z[1]), rr = csub(z[0], z[1]);
          oc4[0*512 + c] = make_float4(pp.x, pp.y, rr.x, rr.y); }
        A4K(1, z[8],  z[9],   C16_1, -S16_1)
        A4K(2, z[4],  z[5],   C16_2, -C16_2)
        A4K(3, z[12], z[13],  S16_1, -C16_1)
        { float2 w = mnegi(z[3]);
          float2 pp = cadd(z[2], w), rr = csub(z[2], w);
          oc4[4*512 + c] = make_float4(pp.x, pp.y, rr.x, rr.y); }
        A4K(5, z[10], z[11], -S16_1, -C16_1)
        A4K(6, z[6],  z[7],  -C16_2, -C16_2)
        A4K(7, z[14], z[15], -C16_1, -S16_1)
        #undef A4K
    }
}

// main conv: each block handles a (d, d+1) pair for one (bp, h).
// FFT #1: z = x[b0,:,d] + i*x[b1,:,d]   (kernel A_d)
// FFT #2: z = x[b0,:,d+1] + i*x[b1,:,d+1] (kernel A_{d+1}) — inputs preloaded in regs.
// Joint float2 stores at the end.
__global__ __launch_bounds__(512, 4) void conv_kernel(
    const float* __restrict__ x, const float2* __restrict__ Afft,
    float* __restrict__ out)
{
    __shared__ __align__(16) float2 Z[NF];   // 64 KB -> 2 blocks/CU
    int blk = blockIdx.x;                    // 1024 blocks
    int c8 = blk & 7, r = blk >> 3;          // r in 0..127
    int dp = ((c8 & 1) << 4) | (r & 15);     // 0..31
    int h  = (((r >> 4) & 3) << 1) | ((c8 >> 1) & 1);
    int bp = (((r >> 6) & 1) << 1) | ((c8 >> 2) & 1);
    int d  = dp * 2;
    int tid = threadIdx.x;
    size_t base0 = ((size_t)((bp*2 + 0)*8 + h) * 4096) * 64 + d;
    size_t base1 = ((size_t)((bp*2 + 1)*8 + h) * 4096) * 64 + d;

    // Load both FFTs' inputs up-front (float2 across d,d+1; FFT#2 latency hidden)
    float2 inA[8], inB[8];
    #pragma unroll
    for (int q = 0; q < 2; ++q) {
        #pragma unroll
        for (int l = 0; l < 4; ++l) {
            int p = tid + q*512 + l*1024;
            float2 f0 = *reinterpret_cast<const float2*>(&x[base0 + (size_t)p*64]);
            float2 f1 = *reinterpret_cast<const float2*>(&x[base1 + (size_t)p*64]);
            inA[q*4+l] = make_float2(f0.x, f1.x);
            inB[q*4+l] = make_float2(f0.y, f1.y);
        }
    }

    const float4* A4a = reinterpret_cast<const float4*>(Afft + (size_t)(h*64 + d    )*NF);
    const float4* A4b = reinterpret_cast<const float4*>(Afft + (size_t)(h*64 + d + 1)*NF);
    float2 outA[8], outB[8];
    fft8192_conv(Z, tid, A4a, inA, outA);
    __syncthreads();
    fft8192_conv(Z, tid, A4b, inB, outB);

    const float sc = 1.0f/8192.0f;
    #pragma unroll
    for (int q = 0; q < 2; ++q) {
        #pragma unroll
        for (int l = 0; l < 4; ++l) {
            int p = tid + q*512 + l*1024;
            float2 yA = outA[q*4+l], yB = outB[q*4+l];
            *reinterpret_cast<float2*>(&out[base0 + (size_t)p*64]) = make_float2(yA.x * sc, yB.x * sc);
            *reinterpret_cast<float2*>(&out[base1 + (size_t)p*64]) = make_float2(yA.y * sc, yB.y * sc);
        }
    }
}

extern "C" void kernel_launch(void* const* d_in, const int* in_sizes, int n_in,
                              void* d_out, int out_size, void* d_ws, size_t ws_size,
                              hipStream_t stream) {
    const float* x   = (const float*)d_in[0];
    const float* pw  = (const float*)d_in[1];
    const float* pb  = (const float*)d_in[2];
    const float* lws = (const float*)d_in[3];
    const float* lbs = (const float*)d_in[4];
    const float* ow  = (const float*)d_in[5];
    const float* ob  = (const float*)d_in[6];
    float* out = (float*)d_out;
    char* ws = (char*)d_ws;
    // ws layout: [0, 16M) a_buf | [16M, 48M) Afft
    float*  a_buf = (float*)ws;
    float2* Afft  = (float2*)(ws + (size_t)512*NF*4);

    rpe_kernel<<<512, 512, 0, stream>>>(pw, pb, lws, lbs, ow, ob, a_buf);
    afft_kernel<<<512, 512, 0, stream>>>(a_buf, Afft);
    conv_kernel<<<1024, 512, 0, stream>>>(x, Afft, out);
}

// Round 5
// 495.480 us; speedup vs baseline: 1.2434x; 1.2434x over previous
//
#include <hip/hip_runtime.h>
#include <math.h>

#define NF 8192

// ---------- complex helpers ----------
__device__ __forceinline__ int phys(int e) { return e ^ (((e >> 4) & 7) << 1); }

__device__ __forceinline__ float2 cmul(float2 a, float2 b) {
    return make_float2(a.x*b.x - a.y*b.y, a.x*b.y + a.y*b.x);
}
__device__ __forceinline__ float2 cmulc(float2 a, float2 b) { // a * conj(b)
    return make_float2(a.x*b.x + a.y*b.y, a.y*b.x - a.x*b.y);
}
__device__ __forceinline__ float2 cadd(float2 a, float2 b){ return make_float2(a.x+b.x, a.y+b.y); }
__device__ __forceinline__ float2 csub(float2 a, float2 b){ return make_float2(a.x-b.x, a.y-b.y); }
__device__ __forceinline__ float2 mnegi(float2 a){ return make_float2(a.y, -a.x); }   // * (-i)
__device__ __forceinline__ float2 mposi(float2 a){ return make_float2(-a.y, a.x); }   // * (+i)
#define RSQ2 0.70710678118654752f
__device__ __forceinline__ float2 mw81 (float2 a){ return make_float2( RSQ2*(a.x+a.y),  RSQ2*(a.y-a.x)); } // * e^{-i pi/4}
__device__ __forceinline__ float2 mw83 (float2 a){ return make_float2( RSQ2*(a.y-a.x), -RSQ2*(a.x+a.y)); } // * e^{-3i pi/4}
__device__ __forceinline__ float2 mw81c(float2 a){ return make_float2( RSQ2*(a.x-a.y),  RSQ2*(a.x+a.y)); } // * e^{+i pi/4}
__device__ __forceinline__ float2 mw83c(float2 a){ return make_float2(-RSQ2*(a.x+a.y),  RSQ2*(a.x-a.y)); } // * e^{+3i pi/4}

// w16 constants
#define C16_1 0.92387953251128674f
#define S16_1 0.38268343236508978f
#define C16_2 0.70710678118654752f

// base twiddle exp(-2*pi*i*ts/8192) via HW transcendentals (input in revolutions, |arg|<1)
__device__ __forceinline__ float2 twbase(int ts) {
    float fa = (float)ts * (1.0f/8192.0f);
    return make_float2(__builtin_amdgcn_cosf(fa), -__builtin_amdgcn_sinf(fa));
}

// DIF radix-8 core. After: y0=v0 y1=v4 y2=v2 y3=v6 y4=v1 y5=v5 y6=v3 y7=v7
__device__ __forceinline__ void dif8_core(float2& v0, float2& v1, float2& v2, float2& v3,
                                          float2& v4, float2& v5, float2& v6, float2& v7) {
    float2 t;
    t = csub(v0, v4); v0 = cadd(v0, v4); v4 = t;
    t = csub(v1, v5); v1 = cadd(v1, v5); v5 = mw81(t);
    t = csub(v2, v6); v2 = cadd(v2, v6); v6 = mnegi(t);
    t = csub(v3, v7); v3 = cadd(v3, v7); v7 = mw83(t);
    t = csub(v0, v2); v0 = cadd(v0, v2); v2 = t;
    t = csub(v1, v3); v1 = cadd(v1, v3); v3 = mnegi(t);
    t = csub(v4, v6); v4 = cadd(v4, v6); v6 = t;
    t = csub(v5, v7); v5 = cadd(v5, v7); v7 = mnegi(t);
    t = csub(v0, v1); v0 = cadd(v0, v1); v1 = t;
    t = csub(v2, v3); v2 = cadd(v2, v3); v3 = t;
    t = csub(v4, v5); v4 = cadd(v4, v5); v5 = t;
    t = csub(v6, v7); v6 = cadd(v6, v7); v7 = t;
}

// DIT radix-8 core. Inputs v0=y0 v1=y4*c4 v2=y2*c2 v3=y6*c6 v4=y1*c1 v5=y5*c5 v6=y3*c3 v7=y7*c7
__device__ __forceinline__ void dit8_core(float2& v0, float2& v1, float2& v2, float2& v3,
                                          float2& v4, float2& v5, float2& v6, float2& v7) {
    float2 t;
    t = csub(v0, v1); v0 = cadd(v0, v1); v1 = t;
    t = csub(v2, v3); v2 = cadd(v2, v3); v3 = t;
    t = csub(v4, v5); v4 = cadd(v4, v5); v5 = t;
    t = csub(v6, v7); v6 = cadd(v6, v7); v7 = t;
    t = v2;        v2 = csub(v0, t); v0 = cadd(v0, t);
    t = mposi(v3); v3 = csub(v1, t); v1 = cadd(v1, t);
    t = v6;        v6 = csub(v4, t); v4 = cadd(v4, t);
    t = mposi(v7); v7 = csub(v5, t); v5 = cadd(v5, t);
    t = v4;        v4 = csub(v0, t); v0 = cadd(v0, t);
    t = mw81c(v5); v5 = csub(v1, t); v1 = cadd(v1, t);
    t = mposi(v6); v6 = csub(v2, t); v2 = cadd(v2, t);
    t = mw83c(v7); v7 = csub(v3, t); v3 = cadd(v3, t);
}

// compute w^1..w^7 from base ts
#define TW_POWERS(ts) \
    float2 w1 = twbase(ts); \
    float2 w2 = cmul(w1, w1); \
    float2 w3 = cmul(w2, w1); \
    float2 w4 = cmul(w2, w2); \
    float2 w5 = cmul(w3, w2); \
    float2 w6 = cmul(w3, w3); \
    float2 w7 = cmul(w4, w3);

// ---------- radix-8 LDS passes (512 threads) ----------
template<int M, int LM>
__device__ __forceinline__ void fwd8_lds(float2* Z, int tid) {
    #pragma unroll
    for (int q = 0; q < 2; ++q) {
        int beta = tid + q*512;
        int i    = beta & (M-1);
        int base = ((beta >> LM) << (LM+3)) + i;
        float2 v0 = Z[phys(base        )];
        float2 v1 = Z[phys(base + 1*M)];
        float2 v2 = Z[phys(base + 2*M)];
        float2 v3 = Z[phys(base + 3*M)];
        float2 v4 = Z[phys(base + 4*M)];
        float2 v5 = Z[phys(base + 5*M)];
        float2 v6 = Z[phys(base + 6*M)];
        float2 v7 = Z[phys(base + 7*M)];
        dif8_core(v0,v1,v2,v3,v4,v5,v6,v7);
        TW_POWERS((NF >> (LM+3)) * i)
        Z[phys(base        )] = v0;
        Z[phys(base + 4*M)] = cmul(v1, w4);
        Z[phys(base + 2*M)] = cmul(v2, w2);
        Z[phys(base + 6*M)] = cmul(v3, w6);
        Z[phys(base + 1*M)] = cmul(v4, w1);
        Z[phys(base + 5*M)] = cmul(v5, w5);
        Z[phys(base + 3*M)] = cmul(v6, w3);
        Z[phys(base + 7*M)] = cmul(v7, w7);
    }
}

template<int M, int LM>
__device__ __forceinline__ void inv8_lds(float2* Z, int tid) {
    #pragma unroll
    for (int q = 0; q < 2; ++q) {
        int beta = tid + q*512;
        int i    = beta & (M-1);
        int base = ((beta >> LM) << (LM+3)) + i;
        TW_POWERS((NF >> (LM+3)) * i)
        float2 v0 = Z[phys(base        )];
        float2 v1 = cmulc(Z[phys(base + 4*M)], w4);
        float2 v2 = cmulc(Z[phys(base + 2*M)], w2);
        float2 v3 = cmulc(Z[phys(base + 6*M)], w6);
        float2 v4 = cmulc(Z[phys(base + 1*M)], w1);
        float2 v5 = cmulc(Z[phys(base + 5*M)], w5);
        float2 v6 = cmulc(Z[phys(base + 3*M)], w3);
        float2 v7 = cmulc(Z[phys(base + 7*M)], w7);
        dit8_core(v0,v1,v2,v3,v4,v5,v6,v7);
        Z[phys(base        )] = v0;
        Z[phys(base + 1*M)] = v1;
        Z[phys(base + 2*M)] = v2;
        Z[phys(base + 3*M)] = v3;
        Z[phys(base + 4*M)] = v4;
        Z[phys(base + 5*M)] = v5;
        Z[phys(base + 6*M)] = v6;
        Z[phys(base + 7*M)] = v7;
    }
}

// ---------- kernels ----------

// Position-MLP: a[c][e] = decay(e) * rpe(offset(e))[c].  512 blocks x 512 thr, 16 pos/block.
__global__ __launch_bounds__(512) void rpe_kernel(
    const float* __restrict__ pw,  const float* __restrict__ pb,
    const float* __restrict__ lws, const float* __restrict__ lbs,
    const float* __restrict__ ow,  const float* __restrict__ ob,
    float* __restrict__ a_buf)
{
    __shared__ float sW2[3][32][64][2];   // 48 KB, layer weights paired-k
    __shared__ float sWo2[32][64][2];     // 16 KB, out-proj chunk paired-k
    __shared__ float sB[3][64];
    __shared__ float sPW[64], sPB[64];
    __shared__ float sAct[8][2][64];      // wave-private activation rows
    int tid = threadIdx.x;
    for (int idx = tid; idx < 3*64*64; idx += 512) {
        int L = idx >> 12, rem = idx & 4095, k = rem >> 6, c = rem & 63;
        sW2[L][k >> 1][c][k & 1] = lws[idx];
    }
    if (tid < 192) ((float*)sB)[tid] = lbs[tid];
    if (tid < 64) { sPW[tid] = pw[tid]; sPB[tid] = pb[tid]; }
    __syncthreads();

    int wv = tid >> 6, lane = tid & 63;
    int e0 = blockIdx.x * 16 + wv * 2;
    float xv[2], dec[2];
    #pragma unroll
    for (int s = 0; s < 2; ++s) {
        int e = e0 + s;
        float p = (e == 4096) ? 0.f : ((e < 4096) ? (float)e : (float)(e - 8192));
        int m = (e < 4096) ? e : (8192 - e);
        if (e == 4096) m = 0;
        dec[s] = exp2f(-0.0014434309482562475f * (float)m);   // log2(0.999)
        xv[s] = fmaf(p, sPW[lane], sPB[lane]);
    }

    #pragma unroll
    for (int L = 0; L < 3; ++L) {
        #pragma unroll
        for (int s = 0; s < 2; ++s) {
            float v = xv[s];
            float ss = v * v;
            #pragma unroll
            for (int o = 1; o < 64; o <<= 1) ss += __shfl_xor(ss, o);
            sAct[wv][s][lane] = fmaxf(v / (sqrtf(ss) * 0.125f + 1e-8f), 0.f);
            float y = sB[L][lane];
            const float2* ap = reinterpret_cast<const float2*>(sAct[wv][s]);
            const float2* wp = reinterpret_cast<const float2*>(sW2[L]);
            #pragma unroll
            for (int kk = 0; kk < 32; ++kk) {
                float2 a2 = ap[kk];
                float2 ww = wp[kk*64 + lane];
                y = fmaf(a2.x, ww.x, y);
                y = fmaf(a2.y, ww.y, y);
            }
            xv[s] = y;
        }
    }
    #pragma unroll
    for (int s = 0; s < 2; ++s) {
        float v = xv[s];
        float ss = v * v;
        #pragma unroll
        for (int o = 1; o < 64; o <<= 1) ss += __shfl_xor(ss, o);
        sAct[wv][s][lane] = fmaxf(v / (sqrtf(ss) * 0.125f + 1e-8f), 0.f);
    }
    for (int qq = 0; qq < 8; ++qq) {
        __syncthreads();
        for (int idx = tid; idx < 4096; idx += 512) {
            int k = idx >> 6, c = idx & 63;
            sWo2[k >> 1][c][k & 1] = ow[(size_t)k*512 + qq*64 + c];
        }
        __syncthreads();
        #pragma unroll
        for (int s = 0; s < 2; ++s) {
            float y = ob[qq*64 + lane];
            const float2* ap = reinterpret_cast<const float2*>(sAct[wv][s]);
            const float2* wp = reinterpret_cast<const float2*>(sWo2);
            #pragma unroll
            for (int kk = 0; kk < 32; ++kk) {
                float2 a2 = ap[kk];
                float2 ww = wp[kk*64 + lane];
                y = fmaf(a2.x, ww.x, y);
                y = fmaf(a2.y, ww.y, y);
            }
            a_buf[(size_t)(qq*64 + lane)*NF + (e0 + s)] = y * dec[s];
        }
    }
}

// FFT of each kernel column -> scrambled-order spectrum, stored transposed [k][c].
__global__ __launch_bounds__(512, 4) void afft_kernel(
    const float* __restrict__ a_buf, float2* __restrict__ Afft)
{
    __shared__ __align__(16) float2 Z[NF];   // 64 KB
    int cc = blockIdx.x, tid = threadIdx.x;
    const float* col = a_buf + (size_t)cc * NF;
    #pragma unroll
    for (int q = 0; q < 2; ++q) {
        int i = tid + q*512;
        float2 v0 = make_float2(col[i       ], 0.f);
        float2 v1 = make_float2(col[i + 1024], 0.f);
        float2 v2 = make_float2(col[i + 2048], 0.f);
        float2 v3 = make_float2(col[i + 3072], 0.f);
        float2 v4 = make_float2(col[i + 4096], 0.f);
        float2 v5 = make_float2(col[i + 5120], 0.f);
        float2 v6 = make_float2(col[i + 6144], 0.f);
        float2 v7 = make_float2(col[i + 7168], 0.f);
        dif8_core(v0,v1,v2,v3,v4,v5,v6,v7);
        TW_POWERS(i)
        Z[phys(i        )] = v0;
        Z[phys(i + 4096)] = cmul(v1, w4);
        Z[phys(i + 2048)] = cmul(v2, w2);
        Z[phys(i + 6144)] = cmul(v3, w6);
        Z[phys(i + 1024)] = cmul(v4, w1);
        Z[phys(i + 5120)] = cmul(v5, w5);
        Z[phys(i + 3072)] = cmul(v6, w3);
        Z[phys(i + 7168)] = cmul(v7, w7);
    }
    __syncthreads();
    fwd8_lds<128, 7>(Z, tid);  __syncthreads();
    fwd8_lds<16,  4>(Z, tid);  __syncthreads();
    {
        int c = tid, sw4 = c & 7;
        float4* Z4 = reinterpret_cast<float4*>(Z);
        float4* oc4 = reinterpret_cast<float4*>(Afft + (size_t)cc * NF);
        float2 z[16];
        #pragma unroll
        for (int j = 0; j < 8; ++j) {
            float4 wv = Z4[c*8 + (j ^ sw4)];
            z[2*j]   = make_float2(wv.x, wv.y);
            z[2*j+1] = make_float2(wv.z, wv.w);
        }
        dif8_core(z[0],z[2],z[4],z[6],z[8],z[10],z[12],z[14]);
        dif8_core(z[1],z[3],z[5],z[7],z[9],z[11],z[13],z[15]);
        #define A4K(k, ZE, ZO, WR, WI) { \
            float2 w = make_float2((WR)*(ZO).x - (WI)*(ZO).y, (WR)*(ZO).y + (WI)*(ZO).x); \
            float2 pp = cadd(ZE, w), rr = csub(ZE, w); \
            oc4[(k)*512 + c] = make_float4(pp.x, pp.y, rr.x, rr.y); }
        { float2 pp = cadd(z[0], z[1]), rr = csub(z[0], z[1]);
          oc4[0*512 + c] = make_float4(pp.x, pp.y, rr.x, rr.y); }
        A4K(1, z[8],  z[9],   C16_1, -S16_1)
        A4K(2, z[4],  z[5],   C16_2, -C16_2)
        A4K(3, z[12], z[13],  S16_1, -C16_1)
        { float2 w = mnegi(z[3]);
          float2 pp = cadd(z[2], w), rr = csub(z[2], w);
          oc4[4*512 + c] = make_float4(pp.x, pp.y, rr.x, rr.y); }
        A4K(5, z[10], z[11], -S16_1, -C16_1)
        A4K(6, z[6],  z[7],  -C16_2, -C16_2)
        A4K(7, z[14], z[15], -C16_1, -S16_1)
        #undef A4K
    }
}

// main conv: z[n] = x[b,h,n,2dp] + i*x[b,h,n,2dp+1] (float2 loads), one batch.
// Spectrum split in P4 recovers E (for channel 2dp) and O (for 2dp+1), multiplies
// by their respective kernel spectra, merges Y = E*Aa + i*O*Ab, then inverse FFT.
// Pairing (k <-> N-k): thread c holds k = l(c) + 512m, m=0..15, l = octal-rev(c);
// partner thread cp = rev((512-l)&511) holds N-k at m' = 15-m (or (16-m)&15 if l==0).
__global__ __launch_bounds__(512, 4) void conv_kernel(
    const float* __restrict__ x, const float2* __restrict__ Afft,
    float* __restrict__ out)
{
    __shared__ __align__(16) float2 Z[NF];   // 64 KB -> 2 blocks/CU
    int blk = blockIdx.x;                    // 2048 blocks
    int b   = blk & 7;                       // XCD id -> one batch per XCD (L2 locality)
    int q   = blk >> 3;                      // 0..255
    int h   = q >> 5;
    int dp  = q & 31;
    int tid = threadIdx.x;
    size_t base = ((size_t)(b*8 + h) * 4096) * 64 + 2*dp;

    // P1: fused float2 load + fwd8<1024,10> (upper half of input zero)
    #pragma unroll
    for (int qq = 0; qq < 2; ++qq) {
        int i = tid + qq*512;
        float2 v0 = *reinterpret_cast<const float2*>(&x[base + (size_t)(i       )*64]);
        float2 v1 = *reinterpret_cast<const float2*>(&x[base + (size_t)(i + 1024)*64]);
        float2 v2 = *reinterpret_cast<const float2*>(&x[base + (size_t)(i + 2048)*64]);
        float2 v3 = *reinterpret_cast<const float2*>(&x[base + (size_t)(i + 3072)*64]);
        float2 v4 = v0;
        float2 v5 = mw81(v1);
        float2 v6 = mnegi(v2);
        float2 v7 = mw83(v3);
        float2 t;
        t = csub(v0, v2); v0 = cadd(v0, v2); v2 = t;
        t = csub(v1, v3); v1 = cadd(v1, v3); v3 = mnegi(t);
        t = csub(v4, v6); v4 = cadd(v4, v6); v6 = t;
        t = csub(v5, v7); v5 = cadd(v5, v7); v7 = mnegi(t);
        t = csub(v0, v1); v0 = cadd(v0, v1); v1 = t;
        t = csub(v2, v3); v2 = cadd(v2, v3); v3 = t;
        t = csub(v4, v5); v4 = cadd(v4, v5); v5 = t;
        t = csub(v6, v7); v6 = cadd(v6, v7); v7 = t;
        TW_POWERS(i)
        Z[phys(i        )] = v0;
        Z[phys(i + 4096)] = cmul(v1, w4);
        Z[phys(i + 2048)] = cmul(v2, w2);
        Z[phys(i + 6144)] = cmul(v3, w6);
        Z[phys(i + 1024)] = cmul(v4, w1);
        Z[phys(i + 5120)] = cmul(v5, w5);
        Z[phys(i + 3072)] = cmul(v6, w3);
        Z[phys(i + 7168)] = cmul(v7, w7);
    }
    __syncthreads();
    fwd8_lds<128, 7>(Z, tid);  __syncthreads();
    fwd8_lds<16,  4>(Z, tid);  __syncthreads();

    // P4: finish fwd (16-pt in regs) -> spectrum split via partner exchange ->
    //     *Aa/*Ab merge -> start inverse (16-pt in regs)
    {
        int c = tid, sw4 = c & 7;
        int l  = (c >> 6) | (((c >> 3) & 7) << 3) | ((c & 7) << 6);
        int lp = (512 - l) & 511;
        int cp = ((lp & 7) << 6) | (((lp >> 3) & 7) << 3) | (lp >> 6);
        int swp = cp & 7;
        bool l0 = (l == 0);
        float4* Z4 = reinterpret_cast<float4*>(Z);
        const float4* A4a = reinterpret_cast<const float4*>(Afft + (size_t)(h*64 + 2*dp    )*NF);
        const float4* A4b = reinterpret_cast<const float4*>(Afft + (size_t)(h*64 + 2*dp + 1)*NF);

        float2 zz[16];
        #pragma unroll
        for (int j = 0; j < 8; ++j) {
            float4 wv = Z4[c*8 + (j ^ sw4)];
            zz[2*j]   = make_float2(wv.x, wv.y);
            zz[2*j+1] = make_float2(wv.z, wv.w);
        }
        dif8_core(zz[0],zz[2],zz[4],zz[6],zz[8],zz[10],zz[12],zz[14]);
        dif8_core(zz[1],zz[3],zz[5],zz[7],zz[9],zz[11],zz[13],zz[15]);
        // final radix-2 combine -> true spectrum S[m], k = l + 512m
        float2 S[16];
        #define SPLIT(kk, JE, WR, WI) { \
            float2 E = zz[2*(JE)], O = zz[2*(JE)+1]; \
            float2 wo = make_float2((WR)*O.x - (WI)*O.y, (WR)*O.y + (WI)*O.x); \
            S[kk] = cadd(E, wo); S[(kk)+8] = csub(E, wo); }
        SPLIT(0, 0,  1.0f,   0.0f)
        SPLIT(1, 4,  C16_1, -S16_1)
        SPLIT(2, 2,  C16_2, -C16_2)
        SPLIT(3, 6,  S16_1, -C16_1)
        SPLIT(4, 1,  0.0f,  -1.0f)
        SPLIT(5, 5, -S16_1, -C16_1)
        SPLIT(6, 3, -C16_2, -C16_2)
        SPLIT(7, 7, -C16_1, -S16_1)
        #undef SPLIT
        // publish S to own chunk: slot j <- (S[rev3(j)], S[rev3(j)+8]); rev3={0,4,2,6,1,5,3,7}
        {
            const int rev3[8] = {0,4,2,6,1,5,3,7};
            #pragma unroll
            for (int j = 0; j < 8; ++j) {
                int m = rev3[j];
                Z4[c*8 + (j ^ sw4)] = make_float4(S[m].x, S[m].y, S[m+8].x, S[m+8].y);
            }
        }
        __syncthreads();
        // read partner's spectrum
        float2 Sp[16];
        {
            const int rev3[8] = {0,4,2,6,1,5,3,7};
            #pragma unroll
            for (int j = 0; j < 8; ++j) {
                float4 wv = Z4[cp*8 + (j ^ swp)];
                int m = rev3[j];
                Sp[m]   = make_float2(wv.x, wv.y);
                Sp[m+8] = make_float2(wv.z, wv.w);
            }
        }
        // Y[m] = E*Aa + i*O*Ab;  fold pairs into inverse-ready zz
        float2 Yv[16];
        #define YPAIR(kk, IA0, IB0, IA8, IB8) { \
            float4 aa = A4a[(kk)*512 + c]; \
            float4 ab = A4b[(kk)*512 + c]; \
            { float2 P = l0 ? Sp[IA0] : Sp[IB0]; \
              float2 E = make_float2(0.5f*(S[kk].x + P.x),  0.5f*(S[kk].y - P.y)); \
              float2 O = make_float2(0.5f*(S[kk].y + P.y), -0.5f*(S[kk].x - P.x)); \
              Yv[kk] = cadd(cmul(E, make_float2(aa.x, aa.y)), mposi(cmul(O, make_float2(ab.x, ab.y)))); } \
            { float2 P = l0 ? Sp[IA8] : Sp[IB8]; \
              float2 E = make_float2(0.5f*(S[(kk)+8].x + P.x),  0.5f*(S[(kk)+8].y - P.y)); \
              float2 O = make_float2(0.5f*(S[(kk)+8].y + P.y), -0.5f*(S[(kk)+8].x - P.x)); \
              Yv[(kk)+8] = cadd(cmul(E, make_float2(aa.z, aa.w)), mposi(cmul(O, make_float2(ab.z, ab.w)))); } }
        YPAIR(0,  0, 15, 8, 7)
        YPAIR(1, 15, 14, 7, 6)
        YPAIR(2, 14, 13, 6, 5)
        YPAIR(3, 13, 12, 5, 4)
        YPAIR(4, 12, 11, 4, 3)
        YPAIR(5, 11, 10, 3, 2)
        YPAIR(6, 10,  9, 2, 1)
        YPAIR(7,  9,  8, 1, 0)
        #undef YPAIR
        // inverse radix-2 + conj twiddles -> zz, then two dit8
        #define GPAIR(kk, JE, WRC, WIC) { \
            float2 GE = cadd(Yv[kk], Yv[(kk)+8]); \
            float2 GO = csub(Yv[kk], Yv[(kk)+8]); \
            zz[2*(JE)]   = GE; \
            zz[2*(JE)+1] = make_float2((WRC)*GO.x - (WIC)*GO.y, (WRC)*GO.y + (WIC)*GO.x); }
        GPAIR(0, 0,  1.0f,  0.0f)
        GPAIR(1, 4,  C16_1, S16_1)
        GPAIR(2, 2,  C16_2, C16_2)
        GPAIR(3, 6,  S16_1, C16_1)
        GPAIR(4, 1,  0.0f,  1.0f)
        GPAIR(5, 5, -S16_1, C16_1)
        GPAIR(6, 3, -C16_2, C16_2)
        GPAIR(7, 7, -C16_1, S16_1)
        #undef GPAIR
        dit8_core(zz[0],zz[2],zz[4],zz[6],zz[8],zz[10],zz[12],zz[14]);
        dit8_core(zz[1],zz[3],zz[5],zz[7],zz[9],zz[11],zz[13],zz[15]);
        __syncthreads();   // partner must finish reading S before we overwrite
        #pragma unroll
        for (int j = 0; j < 8; ++j)
            Z4[c*8 + (j ^ sw4)] = make_float4(zz[2*j].x, zz[2*j].y, zz[2*j+1].x, zz[2*j+1].y);
    }
    __syncthreads();
    inv8_lds<16,  4>(Z, tid);  __syncthreads();
    inv8_lds<128, 7>(Z, tid);  __syncthreads();

    // P7: fused inv8<1024,10> + float2 store (only legs 0..3 kept)
    const float sc = 1.0f/8192.0f;
    #pragma unroll
    for (int qq = 0; qq < 2; ++qq) {
        int i = tid + qq*512;
        TW_POWERS(i)
        float2 v0 = Z[phys(i        )];
        float2 v1 = cmulc(Z[phys(i + 4096)], w4);
        float2 v2 = cmulc(Z[phys(i + 2048)], w2);
        float2 v3 = cmulc(Z[phys(i + 6144)], w6);
        float2 v4 = cmulc(Z[phys(i + 1024)], w1);
        float2 v5 = cmulc(Z[phys(i + 5120)], w5);
        float2 v6 = cmulc(Z[phys(i + 3072)], w3);
        float2 v7 = cmulc(Z[phys(i + 7168)], w7);
        float2 t;
        t = csub(v0, v1); v0 = cadd(v0, v1); v1 = t;
        t = csub(v2, v3); v2 = cadd(v2, v3); v3 = t;
        t = csub(v4, v5); v4 = cadd(v4, v5); v5 = t;
        t = csub(v6, v7); v6 = cadd(v6, v7); v7 = t;
        t = v2;        v2 = csub(v0, t); v0 = cadd(v0, t);
        t = mposi(v3); v3 = csub(v1, t); v1 = cadd(v1, t);
        t = v6;        v6 = csub(v4, t); v4 = cadd(v4, t);
        t = mposi(v7); v7 = csub(v5, t); v5 = cadd(v5, t);
        v0 = cadd(v0, v4);
        v1 = cadd(v1, mw81c(v5));
        v2 = cadd(v2, mposi(v6));
        v3 = cadd(v3, mw83c(v7));
        *reinterpret_cast<float2*>(&out[base + (size_t)(i       )*64]) = make_float2(v0.x*sc, v0.y*sc);
        *reinterpret_cast<float2*>(&out[base + (size_t)(i + 1024)*64]) = make_float2(v1.x*sc, v1.y*sc);
        *reinterpret_cast<float2*>(&out[base + (size_t)(i + 2048)*64]) = make_float2(v2.x*sc, v2.y*sc);
        *reinterpret_cast<float2*>(&out[base + (size_t)(i + 3072)*64]) = make_float2(v3.x*sc, v3.y*sc);
    }
}

extern "C" void kernel_launch(void* const* d_in, const int* in_sizes, int n_in,
                              void* d_out, int out_size, void* d_ws, size_t ws_size,
                              hipStream_t stream) {
    const float* x   = (const float*)d_in[0];
    const float* pw  = (const float*)d_in[1];
    const float* pb  = (const float*)d_in[2];
    const float* lws = (const float*)d_in[3];
    const float* lbs = (const float*)d_in[4];
    const float* ow  = (const float*)d_in[5];
    const float* ob  = (const float*)d_in[6];
    float* out = (float*)d_out;
    char* ws = (char*)d_ws;
    // ws layout: [0, 16M) a_buf | [16M, 48M) Afft
    float*  a_buf = (float*)ws;
    float2* Afft  = (float2*)(ws + (size_t)512*NF*4);

    rpe_kernel<<<512, 512, 0, stream>>>(pw, pb, lws, lbs, ow, ob, a_buf);
    afft_kernel<<<512, 512, 0, stream>>>(a_buf, Afft);
    conv_kernel<<<2048, 512, 0, stream>>>(x, Afft, out);
}